// Round 1
// baseline (357.054 us; speedup 1.0000x reference)
//
#include <hip/hip_runtime.h>
#include <hip/hip_bf16.h>

#define D 128

typedef unsigned short u16;

__device__ __forceinline__ u16 f32_to_bf16(float f) {
    unsigned u = __float_as_uint(f);
    unsigned rounding = 0x7fffu + ((u >> 16) & 1u);   // round-to-nearest-even
    return (u16)((u + rounding) >> 16);
}

__device__ __forceinline__ float bf16_to_f32(u16 s) {
    return __uint_as_float(((unsigned)s) << 16);
}

// -------------------------------------------------------------------------
// Kernel 1: support = x @ W + b, stored as bf16 in workspace.
// Block = 256 threads, computes a 64-row x 128-col tile.
// LDS: x tile fp32 (32 KB) + W as bf16 (32 KB) = 64 KB exactly.
// Thread (tx,ty) with tx in [0,16), ty in [0,16): 4 rows x 8 cols each.
// -------------------------------------------------------------------------
__global__ __launch_bounds__(256) void gemm_bias_kernel(
    const float* __restrict__ x, const float* __restrict__ W,
    const float* __restrict__ b, u16* __restrict__ sup, int N)
{
    __shared__ float xs[64 * 128];
    __shared__ u16   wsh[128 * 128];

    const int tid = threadIdx.x;
    const int tx = tid & 15;
    const int ty = tid >> 4;
    const int rowbase = blockIdx.x * 64;

    // Stage W (fp32 -> bf16): 16384 elements, 16 float4 per thread, coalesced.
    #pragma unroll
    for (int i = 0; i < 16; ++i) {
        int idx = i * 1024 + tid * 4;
        float4 v = *(const float4*)(W + idx);
        ushort4 u;
        u.x = f32_to_bf16(v.x);
        u.y = f32_to_bf16(v.y);
        u.z = f32_to_bf16(v.z);
        u.w = f32_to_bf16(v.w);
        *(ushort4*)(&wsh[idx]) = u;
    }

    // Stage x tile: 64x128 fp32, 8 float4 per thread, coalesced. Guard rows.
    #pragma unroll
    for (int i = 0; i < 8; ++i) {
        int idx = i * 1024 + tid * 4;
        int r = idx >> 7;
        int c = idx & 127;
        int gr = rowbase + r;
        float4 v;
        if (gr < N) v = *(const float4*)(x + (size_t)gr * D + c);
        else        v = make_float4(0.f, 0.f, 0.f, 0.f);
        *(float4*)(&xs[idx]) = v;
    }
    __syncthreads();

    const int c0 = tx * 4;
    const int c1 = 64 + tx * 4;
    const int r0 = ty * 4;

    float acc[4][8];
    #pragma unroll
    for (int i = 0; i < 4; ++i) {
        #pragma unroll
        for (int j = 0; j < 4; ++j) {
            acc[i][j]     = b[c0 + j];
            acc[i][4 + j] = b[c1 + j];
        }
    }

    for (int k4 = 0; k4 < 128; k4 += 4) {
        float av[4][4];
        #pragma unroll
        for (int i = 0; i < 4; ++i) {
            float4 t = *(const float4*)(&xs[(r0 + i) * 128 + k4]);
            av[i][0] = t.x; av[i][1] = t.y; av[i][2] = t.z; av[i][3] = t.w;
        }
        #pragma unroll
        for (int kk = 0; kk < 4; ++kk) {
            ushort4 w0 = *(const ushort4*)(&wsh[(k4 + kk) * 128 + c0]);
            ushort4 w1 = *(const ushort4*)(&wsh[(k4 + kk) * 128 + c1]);
            float wf[8];
            wf[0] = bf16_to_f32(w0.x); wf[1] = bf16_to_f32(w0.y);
            wf[2] = bf16_to_f32(w0.z); wf[3] = bf16_to_f32(w0.w);
            wf[4] = bf16_to_f32(w1.x); wf[5] = bf16_to_f32(w1.y);
            wf[6] = bf16_to_f32(w1.z); wf[7] = bf16_to_f32(w1.w);
            #pragma unroll
            for (int i = 0; i < 4; ++i) {
                #pragma unroll
                for (int j = 0; j < 8; ++j) {
                    acc[i][j] = fmaf(av[i][kk], wf[j], acc[i][j]);
                }
            }
        }
    }

    // Store as bf16, coalesced 8 B / lane.
    #pragma unroll
    for (int i = 0; i < 4; ++i) {
        int gr = rowbase + r0 + i;
        if (gr < N) {
            ushort4 o0, o1;
            o0.x = f32_to_bf16(acc[i][0]); o0.y = f32_to_bf16(acc[i][1]);
            o0.z = f32_to_bf16(acc[i][2]); o0.w = f32_to_bf16(acc[i][3]);
            o1.x = f32_to_bf16(acc[i][4]); o1.y = f32_to_bf16(acc[i][5]);
            o1.z = f32_to_bf16(acc[i][6]); o1.w = f32_to_bf16(acc[i][7]);
            *(ushort4*)(sup + (size_t)gr * D + c0) = o0;
            *(ushort4*)(sup + (size_t)gr * D + c1) = o1;
        }
    }
}

// -------------------------------------------------------------------------
// Kernel 2: row_ptr from sorted edge_dst. rp[n] = lower_bound(edge_dst, n).
// Edge-parallel; gaps between consecutive dst values are ~1 (Poisson deg 32).
// -------------------------------------------------------------------------
__global__ __launch_bounds__(256) void rowptr_kernel(
    const int* __restrict__ edst, int* __restrict__ rp, int E, int N)
{
    int e = blockIdx.x * 256 + threadIdx.x;
    if (e >= E) return;
    int d = edst[e];
    int prev = (e == 0) ? -1 : edst[e - 1];
    for (int n = prev + 1; n <= d; ++n) rp[n] = e;
    if (e == E - 1) {
        for (int n = d + 1; n <= N; ++n) rp[n] = E;
    }
}

// -------------------------------------------------------------------------
// Kernel 3: SpMM. One wave (64 lanes) per destination node; each lane owns
// 2 of the 128 features (one dword of the bf16 support row). Edge metadata
// loads are wave-uniform; the support-row gather is one 256 B aligned row.
// Unrolled x2 so two independent gather chains are in flight.
// -------------------------------------------------------------------------
__global__ __launch_bounds__(256) void spmm_kernel(
    const u16* __restrict__ sup, const float* __restrict__ ew,
    const int* __restrict__ esrc, const int* __restrict__ rp,
    float* __restrict__ out, int N)
{
    const int wid  = (blockIdx.x * 256 + threadIdx.x) >> 6;
    const int lane = threadIdx.x & 63;
    if (wid >= N) return;

    const int start = rp[wid];
    const int end   = rp[wid + 1];

    float acc0 = 0.f, acc1 = 0.f;
    int e = start;
    for (; e + 1 < end; e += 2) {
        int   s0 = esrc[e];
        int   s1 = esrc[e + 1];
        float w0 = ew[e];
        float w1 = ew[e + 1];
        unsigned u0 = *(const unsigned*)(sup + (size_t)s0 * D + lane * 2);
        unsigned u1 = *(const unsigned*)(sup + (size_t)s1 * D + lane * 2);
        acc0 = fmaf(w0, __uint_as_float(u0 << 16), acc0);
        acc1 = fmaf(w0, __uint_as_float(u0 & 0xffff0000u), acc1);
        acc0 = fmaf(w1, __uint_as_float(u1 << 16), acc0);
        acc1 = fmaf(w1, __uint_as_float(u1 & 0xffff0000u), acc1);
    }
    if (e < end) {
        int   s0 = esrc[e];
        float w0 = ew[e];
        unsigned u0 = *(const unsigned*)(sup + (size_t)s0 * D + lane * 2);
        acc0 = fmaf(w0, __uint_as_float(u0 << 16), acc0);
        acc1 = fmaf(w0, __uint_as_float(u0 & 0xffff0000u), acc1);
    }

    float2 o;
    o.x = acc0;
    o.y = acc1;
    *(float2*)(out + (size_t)wid * D + lane * 2) = o;
}

extern "C" void kernel_launch(void* const* d_in, const int* in_sizes, int n_in,
                              void* d_out, int out_size, void* d_ws, size_t ws_size,
                              hipStream_t stream) {
    const float* x    = (const float*)d_in[0];
    const float* W    = (const float*)d_in[1];
    const float* b    = (const float*)d_in[2];
    const float* ew   = (const float*)d_in[3];
    const int*   esrc = (const int*)d_in[4];
    const int*   edst = (const int*)d_in[5];
    float* out = (float*)d_out;

    const int N = in_sizes[0] / D;
    const int E = in_sizes[3];

    u16* sup = (u16*)d_ws;                                   // N*128 bf16 = 25.6 MB
    int* rp  = (int*)((char*)d_ws + (size_t)N * D * sizeof(u16)); // N+1 ints

    hipLaunchKernelGGL(gemm_bias_kernel, dim3((N + 63) / 64), dim3(256), 0, stream,
                       x, W, b, sup, N);
    hipLaunchKernelGGL(rowptr_kernel, dim3((E + 255) / 256), dim3(256), 0, stream,
                       edst, rp, E, N);
    hipLaunchKernelGGL(spmm_kernel, dim3((N + 3) / 4), dim3(256), 0, stream,
                       sup, ew, esrc, rp, out, N);
}

// Round 2
// 275.663 us; speedup vs baseline: 1.2953x; 1.2953x over previous
//
#include <hip/hip_runtime.h>

#define D 128

typedef unsigned short u16;
typedef __attribute__((ext_vector_type(8))) short bf16x8;
typedef __attribute__((ext_vector_type(4))) float f32x4;

__device__ __forceinline__ u16 f32_to_bf16(float f) {
    unsigned u = __float_as_uint(f);
    unsigned rounding = 0x7fffu + ((u >> 16) & 1u);   // round-to-nearest-even
    return (u16)((u + rounding) >> 16);
}

__device__ __forceinline__ float bf16_to_f32(u16 s) {
    return __uint_as_float(((unsigned)s) << 16);
}

// -------------------------------------------------------------------------
// Kernel 0: Wt[n][k] = bf16(W[k][n]).  16384 elements, one block.
// -------------------------------------------------------------------------
__global__ __launch_bounds__(256) void prep_kernel(
    const float* __restrict__ W, u16* __restrict__ Wt)
{
    #pragma unroll 4
    for (int i = 0; i < 64; ++i) {
        int idx = i * 256 + threadIdx.x;     // idx = n*128 + k
        int n = idx >> 7;
        int k = idx & 127;
        Wt[idx] = f32_to_bf16(W[k * 128 + n]);
    }
}

// -------------------------------------------------------------------------
// Kernel 1: support = bf16(x @ W + b) via MFMA 16x16x32 bf16.
// No LDS. Block = 256 (4 waves); wave w owns rows [blk*64 + w*16, +16).
// x is split into hi+lo bf16 parts (2 MFMAs) so x incurs no rounding error;
// only W's bf16 rounding + final bf16 store remain (same as R1's error).
// A-frag: A[m=lane&15][k=quad*8+j]; B-frag: B[k=quad*8+j][n=lane&15];
// C/D: col=lane&15, row=quad*4+reg.
// -------------------------------------------------------------------------
__global__ __launch_bounds__(256) void gemm_mfma_kernel(
    const float* __restrict__ x, const u16* __restrict__ Wt,
    const float* __restrict__ b, u16* __restrict__ sup, int N)
{
    const int lane = threadIdx.x & 63;
    const int wave = threadIdx.x >> 6;
    const int col  = lane & 15;
    const int quad = lane >> 4;
    const int row0 = blockIdx.x * 64 + wave * 16;
    const int m    = row0 + col;
    const bool mvalid = (m < N);

    f32x4 acc[8];
    #pragma unroll
    for (int nt = 0; nt < 8; ++nt) {
        float bias = b[nt * 16 + col];
        acc[nt][0] = bias; acc[nt][1] = bias;
        acc[nt][2] = bias; acc[nt][3] = bias;
    }

    const float* xrow = x + (size_t)m * D;

    #pragma unroll
    for (int ks = 0; ks < 4; ++ks) {
        const int k0 = ks * 32 + quad * 8;

        float af[8];
        if (mvalid) {
            float4 v0 = *(const float4*)(xrow + k0);
            float4 v1 = *(const float4*)(xrow + k0 + 4);
            af[0] = v0.x; af[1] = v0.y; af[2] = v0.z; af[3] = v0.w;
            af[4] = v1.x; af[5] = v1.y; af[6] = v1.z; af[7] = v1.w;
        } else {
            #pragma unroll
            for (int j = 0; j < 8; ++j) af[j] = 0.f;
        }

        bf16x8 ahi, alo;
        #pragma unroll
        for (int j = 0; j < 8; ++j) {
            u16 h = f32_to_bf16(af[j]);
            float r = af[j] - bf16_to_f32(h);
            ahi[j] = (short)h;
            alo[j] = (short)f32_to_bf16(r);
        }

        #pragma unroll
        for (int nt = 0; nt < 8; ++nt) {
            bf16x8 bfrag = *(const bf16x8*)(Wt + (size_t)(nt * 16 + col) * D + k0);
            acc[nt] = __builtin_amdgcn_mfma_f32_16x16x32_bf16(alo, bfrag, acc[nt], 0, 0, 0);
            acc[nt] = __builtin_amdgcn_mfma_f32_16x16x32_bf16(ahi, bfrag, acc[nt], 0, 0, 0);
        }
    }

    #pragma unroll
    for (int reg = 0; reg < 4; ++reg) {
        int r = row0 + quad * 4 + reg;
        if (r < N) {
            #pragma unroll
            for (int nt = 0; nt < 8; ++nt) {
                sup[(size_t)r * D + nt * 16 + col] = f32_to_bf16(acc[nt][reg]);
            }
        }
    }
}

// -------------------------------------------------------------------------
// Kernel 2: row_ptr from sorted edge_dst. rp[n] = lower_bound(edge_dst, n).
// -------------------------------------------------------------------------
__global__ __launch_bounds__(256) void rowptr_kernel(
    const int* __restrict__ edst, int* __restrict__ rp, int E, int N)
{
    int e = blockIdx.x * 256 + threadIdx.x;
    if (e >= E) return;
    int d = edst[e];
    int prev = (e == 0) ? -1 : edst[e - 1];
    for (int n = prev + 1; n <= d; ++n) rp[n] = e;
    if (e == E - 1) {
        for (int n = d + 1; n <= N; ++n) rp[n] = E;
    }
}

// -------------------------------------------------------------------------
// Kernel 3: SpMM. One wave per destination node. Segment metadata is loaded
// coalesced (one edge per lane) and broadcast via __shfl, so the row-gather
// address no longer sits behind a dependent metadata load. 8 independent
// row loads in flight per wave. Lanes past the segment end carry w=0,s=0 so
// cnt is rounded up to x8 with harmless padded loads of row 0.
// -------------------------------------------------------------------------
__global__ __launch_bounds__(256) void spmm_kernel(
    const u16* __restrict__ sup, const float* __restrict__ ew,
    const int* __restrict__ esrc, const int* __restrict__ rp,
    float* __restrict__ out, int N)
{
    const int wid  = (blockIdx.x * 256 + threadIdx.x) >> 6;
    const int lane = threadIdx.x & 63;
    if (wid >= N) return;

    const int start = rp[wid];
    const int end   = rp[wid + 1];
    const unsigned off = lane * 2;

    float acc0 = 0.f, acc1 = 0.f, acc2 = 0.f, acc3 = 0.f;

    for (int base = start; base < end; base += 64) {
        int cnt = end - base;
        if (cnt > 64) cnt = 64;
        int cnt8 = (cnt + 7) & ~7;

        int mi = base + lane;
        int   sv = (mi < end) ? esrc[mi] : 0;
        float wv = (mi < end) ? ew[mi]   : 0.f;

        for (int i = 0; i < cnt8; i += 8) {
            int   s0 = __shfl(sv, i    ), s1 = __shfl(sv, i + 1);
            int   s2 = __shfl(sv, i + 2), s3 = __shfl(sv, i + 3);
            int   s4 = __shfl(sv, i + 4), s5 = __shfl(sv, i + 5);
            int   s6 = __shfl(sv, i + 6), s7 = __shfl(sv, i + 7);
            float w0 = __shfl(wv, i    ), w1 = __shfl(wv, i + 1);
            float w2 = __shfl(wv, i + 2), w3 = __shfl(wv, i + 3);
            float w4 = __shfl(wv, i + 4), w5 = __shfl(wv, i + 5);
            float w6 = __shfl(wv, i + 6), w7 = __shfl(wv, i + 7);

            unsigned u0 = *(const unsigned*)(sup + (size_t)s0 * D + off);
            unsigned u1 = *(const unsigned*)(sup + (size_t)s1 * D + off);
            unsigned u2 = *(const unsigned*)(sup + (size_t)s2 * D + off);
            unsigned u3 = *(const unsigned*)(sup + (size_t)s3 * D + off);
            unsigned u4 = *(const unsigned*)(sup + (size_t)s4 * D + off);
            unsigned u5 = *(const unsigned*)(sup + (size_t)s5 * D + off);
            unsigned u6 = *(const unsigned*)(sup + (size_t)s6 * D + off);
            unsigned u7 = *(const unsigned*)(sup + (size_t)s7 * D + off);

            acc0 = fmaf(w0, __uint_as_float(u0 << 16),          acc0);
            acc1 = fmaf(w0, __uint_as_float(u0 & 0xffff0000u),  acc1);
            acc2 = fmaf(w1, __uint_as_float(u1 << 16),          acc2);
            acc3 = fmaf(w1, __uint_as_float(u1 & 0xffff0000u),  acc3);
            acc0 = fmaf(w2, __uint_as_float(u2 << 16),          acc0);
            acc1 = fmaf(w2, __uint_as_float(u2 & 0xffff0000u),  acc1);
            acc2 = fmaf(w3, __uint_as_float(u3 << 16),          acc2);
            acc3 = fmaf(w3, __uint_as_float(u3 & 0xffff0000u),  acc3);
            acc0 = fmaf(w4, __uint_as_float(u4 << 16),          acc0);
            acc1 = fmaf(w4, __uint_as_float(u4 & 0xffff0000u),  acc1);
            acc2 = fmaf(w5, __uint_as_float(u5 << 16),          acc2);
            acc3 = fmaf(w5, __uint_as_float(u5 & 0xffff0000u),  acc3);
            acc0 = fmaf(w6, __uint_as_float(u6 << 16),          acc0);
            acc1 = fmaf(w6, __uint_as_float(u6 & 0xffff0000u),  acc1);
            acc2 = fmaf(w7, __uint_as_float(u7 << 16),          acc2);
            acc3 = fmaf(w7, __uint_as_float(u7 & 0xffff0000u),  acc3);
        }
    }

    float2 o;
    o.x = acc0 + acc2;
    o.y = acc1 + acc3;
    *(float2*)(out + (size_t)wid * D + lane * 2) = o;
}

extern "C" void kernel_launch(void* const* d_in, const int* in_sizes, int n_in,
                              void* d_out, int out_size, void* d_ws, size_t ws_size,
                              hipStream_t stream) {
    const float* x    = (const float*)d_in[0];
    const float* W    = (const float*)d_in[1];
    const float* b    = (const float*)d_in[2];
    const float* ew   = (const float*)d_in[3];
    const int*   esrc = (const int*)d_in[4];
    const int*   edst = (const int*)d_in[5];
    float* out = (float*)d_out;

    const int N = in_sizes[0] / D;
    const int E = in_sizes[3];

    u16* sup = (u16*)d_ws;                                        // N*128 bf16
    int* rp  = (int*)((char*)d_ws + (size_t)N * D * sizeof(u16)); // N+1 ints
    u16* Wt  = (u16*)((char*)rp + ((size_t)N + 16) * sizeof(int));// 128*128 bf16

    hipLaunchKernelGGL(prep_kernel, dim3(1), dim3(256), 0, stream, W, Wt);
    hipLaunchKernelGGL(gemm_mfma_kernel, dim3((N + 63) / 64), dim3(256), 0, stream,
                       x, Wt, b, sup, N);
    hipLaunchKernelGGL(rowptr_kernel, dim3((E + 255) / 256), dim3(256), 0, stream,
                       edst, rp, E, N);
    hipLaunchKernelGGL(spmm_kernel, dim3((N + 3) / 4), dim3(256), 0, stream,
                       sup, ew, esrc, rp, out, N);
}